// Round 1
// baseline (7127.637 us; speedup 1.0000x reference)
//
#include <hip/hip_runtime.h>
#include <hip/hip_bf16.h>
#include <cmath>

#define LAYERS 4
#define Bb 4
#define Ss 1024
#define Dd 1024
#define Ff 2048
#define Hh 8
#define DHd 128
#define Mm (Bb * Ss)   // 4096 rows
#define EPSf 1e-5f

__device__ __forceinline__ float swish_f(float x) { return x / (1.f + expf(-x)); }
__device__ __forceinline__ float gelu_f(float x) {
  // jax.nn.gelu default: approximate=True (tanh form)
  return 0.5f * x * (1.f + tanhf(0.7978845608028654f * (x + 0.044715f * x * x * x)));
}

// ---------------- LayerNorm: one block per row of D=1024 ----------------
__global__ __launch_bounds__(256) void ln_kernel(const float* __restrict__ x,
                                                 float* __restrict__ out,
                                                 const float* __restrict__ sc,
                                                 const float* __restrict__ bi) {
  const int row = blockIdx.x;
  const int t = threadIdx.x;
  const float4 v = *(const float4*)(x + (size_t)row * Dd + t * 4);
  float s = v.x + v.y + v.z + v.w;
  float s2 = v.x * v.x + v.y * v.y + v.z * v.z + v.w * v.w;
#pragma unroll
  for (int o = 32; o > 0; o >>= 1) { s += __shfl_down(s, o); s2 += __shfl_down(s2, o); }
  __shared__ float ps[4], ps2[4];
  if ((t & 63) == 0) { ps[t >> 6] = s; ps2[t >> 6] = s2; }
  __syncthreads();
  s = ps[0] + ps[1] + ps[2] + ps[3];
  s2 = ps2[0] + ps2[1] + ps2[2] + ps2[3];
  const float mu = s * (1.f / Dd);
  const float var = s2 * (1.f / Dd) - mu * mu;
  const float rstd = rsqrtf(var + EPSf);
  const float4 g = *(const float4*)(sc + t * 4);
  const float4 b = *(const float4*)(bi + t * 4);
  float4 o4;
  o4.x = (v.x - mu) * rstd * g.x + b.x;
  o4.y = (v.y - mu) * rstd * g.y + b.y;
  o4.z = (v.z - mu) * rstd * g.z + b.z;
  o4.w = (v.w - mu) * rstd * g.w + b.w;
  *(float4*)(out + (size_t)row * Dd + t * 4) = o4;
}

// ---------------- RoPE tables ----------------
__global__ void rope_table_kernel(float* __restrict__ ct, float* __restrict__ st) {
  const int i = blockIdx.x * 256 + threadIdx.x;  // < Ss*64
  const int s = i >> 6, f = i & 63;
  const float inv = powf(10000.f, -(float)f / 64.f);
  const float a = (float)s * inv;
  ct[i] = cosf(a);
  st[i] = sinf(a);
}

// ---------------- RoPE apply: Q with +sin, K with -sin ----------------
__global__ void rope_kernel(float* __restrict__ Q, float* __restrict__ K,
                            const float* __restrict__ ct, const float* __restrict__ st) {
  const int idx = blockIdx.x * 256 + threadIdx.x;  // < B*S*H*64 pairs
  const int f = idx & 63;
  const int s = (idx >> 9) & (Ss - 1);
  const size_t base = (size_t)(idx >> 6) * DHd + 2 * f;
  const float c = ct[(s << 6) + f], sn = st[(s << 6) + f];
  float2 q = *(float2*)(Q + base);
  float2 k = *(float2*)(K + base);
  float2 qo, ko;
  qo.x = q.x * c - q.y * sn;
  qo.y = q.x * sn + q.y * c;
  ko.x = k.x * c + k.y * sn;
  ko.y = -k.x * sn + k.y * c;
  *(float2*)(Q + base) = qo;
  *(float2*)(K + base) = ko;
}

// ---------------- GroupNorm over DH=128 per (b,s,h), one wave per row ----------------
__global__ __launch_bounds__(256) void gn_kernel(float* Y, const float* __restrict__ gs,
                                                 const float* __restrict__ gb) {
  const int lane = threadIdx.x & 63;
  const int rowh = blockIdx.x * 4 + (threadIdx.x >> 6);  // (b*S+s)*H + h
  const int h = rowh & 7;
  const size_t base = (size_t)(rowh >> 3) * Dd + (size_t)h * DHd + lane * 2;
  float2 v = *(float2*)(Y + base);
  float s = v.x + v.y, s2 = v.x * v.x + v.y * v.y;
#pragma unroll
  for (int o = 32; o > 0; o >>= 1) { s += __shfl_down(s, o); s2 += __shfl_down(s2, o); }
  s = __shfl(s, 0);
  s2 = __shfl(s2, 0);
  const float mu = s * (1.f / DHd);
  const float rstd = rsqrtf(s2 * (1.f / DHd) - mu * mu + EPSf);
  const int d = h * DHd + lane * 2;
  const float2 g = *(const float2*)(gs + d);
  const float2 bb = *(const float2*)(gb + d);
  v.x = (v.x - mu) * rstd * g.x + bb.x;
  v.y = (v.y - mu) * rstd * g.y + bb.y;
  *(float2*)(Y + base) = v;
}

// ---------------- GEMM: C[M,N] = epi(A[M,K] @ W[K,N]) ----------------
// EPI: 0=none, 1=+Res, 2=gelu, 3=swish(.)*Mul
// BM=64, BN=128, BK=8; 256 threads; 4x8 per-thread tile
template <int EPI>
__global__ __launch_bounds__(256) void gemm_kernel(const float* __restrict__ A,
                                                   const float* __restrict__ W,
                                                   float* C, const float* Res,
                                                   const float* __restrict__ Mul,
                                                   int N, int K) {
  __shared__ float As[8][68];
  __shared__ float Bs[8][132];
  const int t = threadIdx.x;
  const int row0 = blockIdx.y * 64;
  const int col0 = blockIdx.x * 128;
  const int tr = t >> 4;  // 0..15 -> 4 rows each
  const int tc = t & 15;  // 0..15 -> 8 cols each
  float acc[4][8];
#pragma unroll
  for (int i = 0; i < 4; ++i)
#pragma unroll
    for (int j = 0; j < 8; ++j) acc[i][j] = 0.f;

  const float* Ap = A + (size_t)(row0 + (t >> 1)) * K + (t & 1) * 4;  // used by t<128
  const float* Wp = W + (size_t)(t >> 5) * N + col0 + (t & 31) * 4;

  for (int k0 = 0; k0 < K; k0 += 8) {
    float4 av = make_float4(0.f, 0.f, 0.f, 0.f);
    if (t < 128) av = *(const float4*)(Ap + k0);
    const float4 bv = *(const float4*)(Wp + (size_t)k0 * N);
    __syncthreads();  // previous iteration's compute done before overwrite
    if (t < 128) {
      const int kk = (t & 1) * 4, mm = t >> 1;
      As[kk + 0][mm] = av.x;
      As[kk + 1][mm] = av.y;
      As[kk + 2][mm] = av.z;
      As[kk + 3][mm] = av.w;
    }
    *(float4*)&Bs[t >> 5][(t & 31) * 4] = bv;
    __syncthreads();
#pragma unroll
    for (int k = 0; k < 8; ++k) {
      float a[4], b[8];
      *(float4*)a = *(const float4*)&As[k][tr * 4];
      *(float4*)b = *(const float4*)&Bs[k][tc * 8];
      *(float4*)(b + 4) = *(const float4*)&Bs[k][tc * 8 + 4];
#pragma unroll
      for (int i = 0; i < 4; ++i)
#pragma unroll
        for (int j = 0; j < 8; ++j) acc[i][j] += a[i] * b[j];
    }
  }
#pragma unroll
  for (int i = 0; i < 4; ++i) {
    const size_t r = row0 + tr * 4 + i;
#pragma unroll
    for (int j = 0; j < 8; j += 4) {
      const size_t o = r * N + col0 + tc * 8 + j;
      float4 v = make_float4(acc[i][j], acc[i][j + 1], acc[i][j + 2], acc[i][j + 3]);
      if (EPI == 1) {
        const float4 rr = *(const float4*)(Res + o);
        v.x += rr.x; v.y += rr.y; v.z += rr.z; v.w += rr.w;
      } else if (EPI == 2) {
        v.x = gelu_f(v.x); v.y = gelu_f(v.y); v.z = gelu_f(v.z); v.w = gelu_f(v.w);
      } else if (EPI == 3) {
        const float4 mm = *(const float4*)(Mul + o);
        v.x = swish_f(v.x) * mm.x;
        v.y = swish_f(v.y) * mm.y;
        v.z = swish_f(v.z) * mm.z;
        v.w = swish_f(v.w) * mm.w;
      }
      *(float4*)(C + o) = v;
    }
  }
}

// ---------------- Retention: per (b,h), 32 q-rows per block, stream K/V in 32-row tiles ----------------
__global__ __launch_bounds__(256) void retention_kernel(const float* __restrict__ Q,
                                                        const float* __restrict__ K,
                                                        const float* __restrict__ V,
                                                        float* __restrict__ Y) {
  __shared__ float Qs[32][132];
  __shared__ float Ks[32][132];
  __shared__ float Vs[32][132];
  __shared__ float Sc[32][33];
  const int t = threadIdx.x;
  const int bh = blockIdx.y;  // b*H + h
  const int b = bh >> 3, h = bh & 7;
  const int n0 = blockIdx.x * 32;
  const float lstep = (logf(1.f / 512.f) - logf(1.f / 32.f)) / 7.f;
  const float gamma = 1.f - expf(logf(1.f / 32.f) + (float)h * lstep);
  const float lg = logf(gamma);
  const size_t hoff = (size_t)h * DHd;

  // load Q tile: 32 rows x 128 = 4 float4 per thread
  const float* Qg = Q + ((size_t)(b * Ss + n0)) * Dd + hoff;
#pragma unroll
  for (int i = 0; i < 4; ++i) {
    const int li = t + 256 * i;
    const int r = li >> 5, c = (li & 31) * 4;
    *(float4*)&Qs[r][c] = *(const float4*)(Qg + (size_t)r * Dd + c);
  }
  const int n = t & 31;
  const int sgrp = t >> 5;  // 0..7
  const int ng = n0 + n;
  float y[16];
#pragma unroll
  for (int j = 0; j < 16; ++j) y[j] = 0.f;
  __syncthreads();

  for (int m0 = 0; m0 < n0 + 32; m0 += 32) {
    const float* Kg = K + ((size_t)(b * Ss + m0)) * Dd + hoff;
    const float* Vg = V + ((size_t)(b * Ss + m0)) * Dd + hoff;
    float4 kv[4], vv[4];
#pragma unroll
    for (int i = 0; i < 4; ++i) {
      const int li = t + 256 * i;
      const int r = li >> 5, c = (li & 31) * 4;
      kv[i] = *(const float4*)(Kg + (size_t)r * Dd + c);
      vv[i] = *(const float4*)(Vg + (size_t)r * Dd + c);
    }
    __syncthreads();  // previous Y-phase done reading Vs/Sc
#pragma unroll
    for (int i = 0; i < 4; ++i) {
      const int li = t + 256 * i;
      const int r = li >> 5, c = (li & 31) * 4;
      *(float4*)&Ks[r][c] = kv[i];
      *(float4*)&Vs[r][c] = vv[i];
    }
    __syncthreads();
    // scores: thread computes 4 scores (row n, cols m0+sgrp*4..+4)
    float sc4[4] = {0.f, 0.f, 0.f, 0.f};
#pragma unroll 4
    for (int d = 0; d < 128; d += 4) {
      const float4 q = *(const float4*)&Qs[n][d];
#pragma unroll
      for (int j = 0; j < 4; ++j) {
        const float4 kk = *(const float4*)&Ks[sgrp * 4 + j][d];
        sc4[j] += q.x * kk.x + q.y * kk.y + q.z * kk.z + q.w * kk.w;
      }
    }
#pragma unroll
    for (int j = 0; j < 4; ++j) {
      const int mg = m0 + sgrp * 4 + j;
      const int df = ng - mg;
      Sc[n][sgrp * 4 + j] = (df >= 0) ? sc4[j] * expf((float)df * lg) : 0.f;
    }
    __syncthreads();
    // Y accumulate: thread owns (row n, d-range sgrp*16..+16)
#pragma unroll 4
    for (int m = 0; m < 32; ++m) {
      const float w = Sc[n][m];
#pragma unroll
      for (int j = 0; j < 16; j += 4) {
        const float4 v4 = *(const float4*)&Vs[m][sgrp * 16 + j];
        y[j] += w * v4.x;
        y[j + 1] += w * v4.y;
        y[j + 2] += w * v4.z;
        y[j + 3] += w * v4.w;
      }
    }
  }
  float* Yg = Y + ((size_t)(b * Ss + n0)) * Dd + hoff;
#pragma unroll
  for (int j = 0; j < 16; j += 4) {
    *(float4*)(Yg + (size_t)n * Dd + sgrp * 16 + j) =
        make_float4(y[j], y[j + 1], y[j + 2], y[j + 3]);
  }
}

extern "C" void kernel_launch(void* const* d_in, const int* in_sizes, int n_in,
                              void* d_out, int out_size, void* d_ws, size_t ws_size,
                              hipStream_t stream) {
  const float* X = (const float*)d_in[0];
  const float* Wq = (const float*)d_in[1];
  const float* Wk = (const float*)d_in[2];
  const float* Wv = (const float*)d_in[3];
  const float* Wg = (const float*)d_in[4];
  const float* Wo = (const float*)d_in[5];
  const float* W1 = (const float*)d_in[6];
  const float* W2 = (const float*)d_in[7];
  const float* lns = (const float*)d_in[8];
  const float* lnb = (const float*)d_in[9];
  const float* gns = (const float*)d_in[10];
  const float* gnb = (const float*)d_in[11];
  float* out = (float*)d_out;

  float* ws = (float*)d_ws;
  const size_t MD = (size_t)Mm * Dd;  // 4M floats
  float* Abuf = ws;                   // running activations
  float* Xn = Abuf + MD;
  float* Qb = Xn + MD;
  float* Kb = Qb + MD;
  float* Vb = Kb + MD;
  float* Yb = Vb + MD;
  float* Hf = Yb + MD;                // M*F floats
  float* ct = Hf + (size_t)Mm * Ff;
  float* st = ct + (size_t)Ss * 64;

  hipMemcpyAsync(Abuf, X, MD * sizeof(float), hipMemcpyDeviceToDevice, stream);
  rope_table_kernel<<<(Ss * 64) / 256, 256, 0, stream>>>(ct, st);

  const dim3 gD(Dd / 128, Mm / 64);
  const dim3 gF(Ff / 128, Mm / 64);

  for (int l = 0; l < LAYERS; ++l) {
    const float* wq = Wq + (size_t)l * Dd * Dd;
    const float* wk = Wk + (size_t)l * Dd * Dd;
    const float* wv = Wv + (size_t)l * Dd * Dd;
    const float* wg = Wg + (size_t)l * Dd * Dd;
    const float* wo = Wo + (size_t)l * Dd * Dd;
    const float* w1 = W1 + (size_t)l * Dd * Ff;
    const float* w2 = W2 + (size_t)l * Ff * Dd;

    // Xn = LN(A)
    ln_kernel<<<Mm, 256, 0, stream>>>(Abuf, Xn, lns, lnb);
    // Q,K,V projections
    gemm_kernel<0><<<gD, 256, 0, stream>>>(Xn, wq, Qb, nullptr, nullptr, Dd, Dd);
    gemm_kernel<0><<<gD, 256, 0, stream>>>(Xn, wk, Kb, nullptr, nullptr, Dd, Dd);
    gemm_kernel<0><<<gD, 256, 0, stream>>>(Xn, wv, Vb, nullptr, nullptr, Dd, Dd);
    // RoPE
    rope_kernel<<<(Bb * Ss * Hh * 64) / 256, 256, 0, stream>>>(Qb, Kb, ct, st);
    // retention -> Yb
    retention_kernel<<<dim3(Ss / 32, Bb * Hh), 256, 0, stream>>>(Qb, Kb, Vb, Yb);
    // groupnorm in place
    gn_kernel<<<(Bb * Ss * Hh) / 4, 256, 0, stream>>>(Yb, gns + (size_t)l * Dd,
                                                      gnb + (size_t)l * Dd);
    // G = swish(Xn@Wg) * Yn  (reuse Qb)
    gemm_kernel<3><<<gD, 256, 0, stream>>>(Xn, wg, Qb, nullptr, Yb, Dd, Dd);
    // A = G@Wo + A  (in place)
    gemm_kernel<1><<<gD, 256, 0, stream>>>(Qb, wo, Abuf, Abuf, nullptr, Dd, Dd);
    // FFN
    ln_kernel<<<Mm, 256, 0, stream>>>(Abuf, Xn, lns, lnb);
    gemm_kernel<2><<<gF, 256, 0, stream>>>(Xn, w1, Hf, nullptr, nullptr, Ff, Dd);
    float* dst = (l == LAYERS - 1) ? out : Abuf;
    gemm_kernel<1><<<gD, 256, 0, stream>>>(Hf, w2, dst, Abuf, nullptr, Dd, Ff);
  }
}

// Round 2
// 1157.057 us; speedup vs baseline: 6.1601x; 6.1601x over previous
//
#include <hip/hip_runtime.h>
#include <hip/hip_bf16.h>
#include <cmath>

#define LAYERS 4
#define Bb 4
#define Ss 1024
#define Dd 1024
#define Ff 2048
#define Hh 8
#define DHd 128
#define Mm (Bb * Ss)   // 4096 rows
#define EPSf 1e-5f

typedef __attribute__((ext_vector_type(8))) short short8v;
typedef __attribute__((ext_vector_type(4))) float f32x4;

__device__ __forceinline__ float swish_f(float x) { return x / (1.f + expf(-x)); }
__device__ __forceinline__ float gelu_f(float x) {
  return 0.5f * x * (1.f + tanhf(0.7978845608028654f * (x + 0.044715f * x * x * x)));
}
__device__ __forceinline__ unsigned short f2bfu(float f) {
  __hip_bfloat16 h = __float2bfloat16(f);
  return __builtin_bit_cast(unsigned short, h);
}
__device__ __forceinline__ void gl_lds16(const void* g, void* l) {
  __builtin_amdgcn_global_load_lds((__attribute__((address_space(1))) void*)g,
                                   (__attribute__((address_space(3))) void*)l, 16, 0, 0);
}
__device__ __forceinline__ f32x4 mfma16(short8v a, short8v b, f32x4 c) {
  return __builtin_amdgcn_mfma_f32_16x16x32_bf16(a, b, c, 0, 0, 0);
}

// ---------------- LayerNorm fp32 -> bf16 ----------------
__global__ __launch_bounds__(256) void ln_bf16_kernel(const float* __restrict__ x,
                                                      short* __restrict__ outb,
                                                      const float* __restrict__ sc,
                                                      const float* __restrict__ bi) {
  const int row = blockIdx.x;
  const int t = threadIdx.x;
  const float4 v = *(const float4*)(x + (size_t)row * Dd + t * 4);
  float s = v.x + v.y + v.z + v.w;
  float s2 = v.x * v.x + v.y * v.y + v.z * v.z + v.w * v.w;
#pragma unroll
  for (int o = 32; o > 0; o >>= 1) { s += __shfl_down(s, o); s2 += __shfl_down(s2, o); }
  __shared__ float ps[4], ps2[4];
  if ((t & 63) == 0) { ps[t >> 6] = s; ps2[t >> 6] = s2; }
  __syncthreads();
  s = ps[0] + ps[1] + ps[2] + ps[3];
  s2 = ps2[0] + ps2[1] + ps2[2] + ps2[3];
  const float mu = s * (1.f / Dd);
  const float var = s2 * (1.f / Dd) - mu * mu;
  const float rstd = rsqrtf(var + EPSf);
  const float4 g = *(const float4*)(sc + t * 4);
  const float4 b = *(const float4*)(bi + t * 4);
  const float o0 = (v.x - mu) * rstd * g.x + b.x;
  const float o1 = (v.y - mu) * rstd * g.y + b.y;
  const float o2 = (v.z - mu) * rstd * g.z + b.z;
  const float o3 = (v.w - mu) * rstd * g.w + b.w;
  unsigned p0 = (unsigned)f2bfu(o0) | ((unsigned)f2bfu(o1) << 16);
  unsigned p1 = (unsigned)f2bfu(o2) | ((unsigned)f2bfu(o3) << 16);
  uint2 pk; pk.x = p0; pk.y = p1;
  *(uint2*)(outb + (size_t)row * Dd + t * 4) = pk;
}

// ---------------- RoPE tables ----------------
__global__ void rope_table_kernel(float* __restrict__ ct, float* __restrict__ st) {
  const int i = blockIdx.x * 256 + threadIdx.x;  // < Ss*64
  const int s = i >> 6, f = i & 63;
  const float inv = powf(10000.f, -(float)f / 64.f);
  const float a = (float)s * inv;
  ct[i] = cosf(a);
  st[i] = sinf(a);
}

// ---------------- RoPE apply fp32 -> bf16 (Q:+sin, K:-sin) ----------------
__global__ void rope_bf16_kernel(const float* __restrict__ Qf, const float* __restrict__ Kf,
                                 short* __restrict__ Qo, short* __restrict__ Ko,
                                 const float* __restrict__ ct, const float* __restrict__ st) {
  const int idx = blockIdx.x * 256 + threadIdx.x;  // < B*S*H*64 pairs
  const int f = idx & 63;
  const int s = (idx >> 9) & (Ss - 1);
  const size_t base = (size_t)(idx >> 6) * DHd + 2 * f;
  const float c = ct[(s << 6) + f], sn = st[(s << 6) + f];
  const float2 q = *(const float2*)(Qf + base);
  const float2 k = *(const float2*)(Kf + base);
  unsigned qp = (unsigned)f2bfu(q.x * c - q.y * sn) | ((unsigned)f2bfu(q.x * sn + q.y * c) << 16);
  unsigned kp = (unsigned)f2bfu(k.x * c + k.y * sn) | ((unsigned)f2bfu(-k.x * sn + k.y * c) << 16);
  *(unsigned*)(Qo + base) = qp;
  *(unsigned*)(Ko + base) = kp;
}

// ---------------- transpose-convert: W[K][N] fp32 -> Wt[N][K] bf16 ----------------
__global__ __launch_bounds__(256) void wtrans_kernel(const float* __restrict__ W,
                                                     short* __restrict__ Wt, int K, int N) {
  __shared__ float tile[32][33];
  const int t = threadIdx.x;
  const int n0 = blockIdx.x * 32, k0 = blockIdx.y * 32;
  const int tc = t & 31, tr8 = t >> 5;
#pragma unroll
  for (int i = 0; i < 4; ++i) {
    const int r = tr8 + i * 8;
    tile[r][tc] = W[(size_t)(k0 + r) * N + n0 + tc];
  }
  __syncthreads();
#pragma unroll
  for (int i = 0; i < 4; ++i) {
    const int r = tr8 + i * 8;
    Wt[(size_t)(n0 + r) * K + k0 + tc] = (short)f2bfu(tile[tc][r]);
  }
}

// ---------------- V transpose: Vf fp32 [B*S][D] -> Vt bf16 [(b,h,dh)][S] ----------------
__global__ __launch_bounds__(256) void vtrans_kernel(const float* __restrict__ Vf,
                                                     short* __restrict__ Vt) {
  __shared__ float tile[32][33];
  const int t = threadIdx.x;
  const int s0 = blockIdx.x * 32, d0 = blockIdx.y * 32, bh = blockIdx.z;
  const int bb = bh >> 3, h = bh & 7;
  const int tc = t & 31, tr8 = t >> 5;
#pragma unroll
  for (int i = 0; i < 4; ++i) {
    const int r = tr8 + i * 8;
    tile[r][tc] = Vf[(size_t)(bb * Ss + s0 + r) * Dd + h * DHd + d0 + tc];
  }
  __syncthreads();
#pragma unroll
  for (int i = 0; i < 4; ++i) {
    const int r = tr8 + i * 8;
    Vt[(size_t)(bh * DHd + d0 + r) * Ss + s0 + tc] = (short)f2bfu(tile[tc][r]);
  }
}

// ---------------- bf16 MFMA GEMM: C[M,N] = epi(A[M,K] @ Wt[N,K]^T) ----------------
// BM=64, BN=128, BK=32; 256 threads (4 waves, 2x2), wave tile 32x64 (2x4 frags)
// EPI: 0 none(f32), 1 +Res(f32), 2 gelu(bf16), 3 swish*Mul(bf16)
template <int EPI, bool BOUT>
__global__ __launch_bounds__(256) void gemm_bf16(const short* __restrict__ A,
                                                 const short* __restrict__ Wt,
                                                 float* __restrict__ Cf,
                                                 short* __restrict__ Cb,
                                                 const float* __restrict__ Res,
                                                 const float* __restrict__ Mul,
                                                 int N, int K) {
  __shared__ __align__(16) short As[64 * 32];
  __shared__ __align__(16) short Bs[128 * 32];
  const int t = threadIdx.x;
  const int w = t >> 6, l = t & 63;
  const int lq = l >> 4, lr = l & 15;
  const int wr = w >> 1, wc = w & 1;
  const int row0 = blockIdx.y * 64, col0 = blockIdx.x * 128;
  f32x4 acc[2][4] = {};

  // staging addresses (chunk-swizzled source, linear LDS dest)
  const int ar = t >> 2, ac = t & 3;
  const short* Ag = A + (size_t)(row0 + ar) * K + ((ac ^ ((ar >> 1) & 3)) << 3);
  const int br = t >> 2, bc = t & 3;
  const short* Bg0 = Wt + (size_t)(col0 + br) * K + ((bc ^ ((br >> 1) & 3)) << 3);
  const int br2 = br + 64;
  const short* Bg1 = Wt + (size_t)(col0 + br2) * K + ((bc ^ ((br2 >> 1) & 3)) << 3);

  for (int k0 = 0; k0 < K; k0 += 32) {
    __syncthreads();
    gl_lds16(Ag + k0, &As[w << 9]);
    gl_lds16(Bg0 + k0, &Bs[w << 9]);
    gl_lds16(Bg1 + k0, &Bs[2048 + (w << 9)]);
    __syncthreads();
    short8v a[2], b[4];
#pragma unroll
    for (int m = 0; m < 2; ++m) {
      const int row = wr * 32 + m * 16 + lr;
      a[m] = *(const short8v*)&As[row * 32 + ((lq ^ ((row >> 1) & 3)) << 3)];
    }
#pragma unroll
    for (int n = 0; n < 4; ++n) {
      const int col = wc * 64 + n * 16 + lr;
      b[n] = *(const short8v*)&Bs[col * 32 + ((lq ^ ((col >> 1) & 3)) << 3)];
    }
#pragma unroll
    for (int m = 0; m < 2; ++m)
#pragma unroll
      for (int n = 0; n < 4; ++n) acc[m][n] = mfma16(a[m], b[n], acc[m][n]);
  }
#pragma unroll
  for (int m = 0; m < 2; ++m) {
#pragma unroll
    for (int n = 0; n < 4; ++n) {
#pragma unroll
      for (int r = 0; r < 4; ++r) {
        const int row = row0 + wr * 32 + m * 16 + lq * 4 + r;
        const int col = col0 + wc * 64 + n * 16 + lr;
        const size_t o = (size_t)row * N + col;
        float v = acc[m][n][r];
        if (EPI == 1) v += Res[o];
        else if (EPI == 2) v = gelu_f(v);
        else if (EPI == 3) v = swish_f(v) * Mul[o];
        if (BOUT) Cb[o] = (short)f2bfu(v);
        else Cf[o] = v;
      }
    }
  }
}

// ---------------- Retention (MFMA) + fused GroupNorm ----------------
// grid (B*H, S/64); 256 threads = 4 waves, each wave owns 16 q-rows.
__global__ __launch_bounds__(256) void ret_kernel(const short* __restrict__ Qb,
                                                  const short* __restrict__ Kb,
                                                  const short* __restrict__ Vt,
                                                  float* __restrict__ Y,
                                                  const float* __restrict__ gns,
                                                  const float* __restrict__ gnb) {
  __shared__ __align__(16) short Ks[32 * 128];
  __shared__ __align__(16) short Vs[128 * 32];
  __shared__ __align__(16) short Sd[4][16 * 40];
  const int t = threadIdx.x, w = t >> 6, l = t & 63;
  const int lq = l >> 4, lr = l & 15;
  const int bh = blockIdx.x, b = bh >> 3, h = bh & 7;
  const int q0 = blockIdx.y * 64;
  const int wq = q0 + w * 16;
  const float lstep = (logf(1.f / 512.f) - logf(1.f / 32.f)) * (1.f / 7.f);
  const float gamma = 1.f - expf(logf(1.f / 32.f) + (float)h * lstep);
  const float l2g = logf(gamma) * 1.44269504f;  // log2(gamma)

  // Q fragments straight from global into registers (A-layout, contiguous k)
  short8v qf[4];
#pragma unroll
  for (int ks = 0; ks < 4; ++ks)
    qf[ks] = *(const short8v*)(Qb + (size_t)(b * Ss + wq + lr) * Dd + h * DHd + ks * 32 + lq * 8);

  f32x4 yacc[8] = {};
  const int ntiles = (q0 >> 5) + 2;
  for (int tile = 0; tile < ntiles; ++tile) {
    const int m0 = tile * 32;
    __syncthreads();
    // stage K tile 32x128 (row-swizzled chunks: slot = c ^ (r&7))
#pragma unroll
    for (int it = 0; it < 2; ++it) {
      const int cid = it * 256 + t, r = cid >> 4, c = cid & 15;
      const short* g = Kb + (size_t)(b * Ss + m0 + r) * Dd + h * DHd + ((c ^ (r & 7)) << 3);
      gl_lds16(g, &Ks[(it * 256 + w * 64) * 8]);
    }
    // stage Vt tile 128x32 (slot = c ^ ((r>>1)&3))
#pragma unroll
    for (int it = 0; it < 2; ++it) {
      const int cid = it * 256 + t, r = cid >> 2, c = cid & 3;
      const short* g = Vt + (size_t)(bh * DHd + r) * Ss + m0 + ((c ^ ((r >> 1) & 3)) << 3);
      gl_lds16(g, &Vs[(it * 256 + w * 64) * 8]);
    }
    __syncthreads();
    // S = Q K^T  (2 col-frags x 4 k-steps)
    f32x4 s[2] = {};
#pragma unroll
    for (int n = 0; n < 2; ++n) {
#pragma unroll
      for (int ks = 0; ks < 4; ++ks) {
        const int row = n * 16 + lr;
        const int ch = ks * 4 + lq;
        short8v bk = *(const short8v*)&Ks[row * 128 + ((ch ^ (row & 7)) << 3)];
        s[n] = mfma16(qf[ks], bk, s[n]);
      }
    }
    // decay mask + bf16 pack into per-wave Sd (A-layout redistribution)
#pragma unroll
    for (int n = 0; n < 2; ++n) {
#pragma unroll
      for (int r = 0; r < 4; ++r) {
        const int qg = wq + lq * 4 + r;
        const int kg = m0 + n * 16 + lr;
        const float wgt = (qg >= kg) ? exp2f((float)(qg - kg) * l2g) : 0.f;
        Sd[w][(lq * 4 + r) * 40 + n * 16 + lr] = (short)f2bfu(s[n][r] * wgt);
      }
    }
    // Y += Sd @ V   (1 a-frag, 8 d-frags)
    short8v av = *(const short8v*)&Sd[w][lr * 40 + lq * 8];
#pragma unroll
    for (int nd = 0; nd < 8; ++nd) {
      const int rowd = nd * 16 + lr;
      short8v bv = *(const short8v*)&Vs[rowd * 32 + ((lq ^ ((rowd >> 1) & 3)) << 3)];
      yacc[nd] = mfma16(av, bv, yacc[nd]);
    }
  }
  // fused GroupNorm over DH=128 (16-lane groups hold a full row across 8 frags)
#pragma unroll
  for (int r = 0; r < 4; ++r) {
    float s1 = 0.f, s2 = 0.f;
#pragma unroll
    for (int nd = 0; nd < 8; ++nd) { const float v = yacc[nd][r]; s1 += v; s2 += v * v; }
#pragma unroll
    for (int msk = 1; msk < 16; msk <<= 1) { s1 += __shfl_xor(s1, msk); s2 += __shfl_xor(s2, msk); }
    const float mu = s1 * (1.f / 128.f);
    const float rstd = rsqrtf(s2 * (1.f / 128.f) - mu * mu + EPSf);
    const int qg = wq + lq * 4 + r;
    float* yp = Y + (size_t)(b * Ss + qg) * Dd + h * DHd;
#pragma unroll
    for (int nd = 0; nd < 8; ++nd) {
      const int d = nd * 16 + lr;
      yp[d] = (yacc[nd][r] - mu) * rstd * gns[h * DHd + d] + gnb[h * DHd + d];
    }
  }
}

extern "C" void kernel_launch(void* const* d_in, const int* in_sizes, int n_in,
                              void* d_out, int out_size, void* d_ws, size_t ws_size,
                              hipStream_t stream) {
  const float* X = (const float*)d_in[0];
  const float* Wq = (const float*)d_in[1];
  const float* Wk = (const float*)d_in[2];
  const float* Wv = (const float*)d_in[3];
  const float* Wg = (const float*)d_in[4];
  const float* Wo = (const float*)d_in[5];
  const float* W1 = (const float*)d_in[6];
  const float* W2 = (const float*)d_in[7];
  const float* lns = (const float*)d_in[8];
  const float* lnb = (const float*)d_in[9];
  const float* gns = (const float*)d_in[10];
  const float* gnb = (const float*)d_in[11];
  float* out = (float*)d_out;

  char* W = (char*)d_ws;
  const size_t MB = 1u << 20;
  float* Abuf = (float*)(W);
  float* Yf = (float*)(W + 16 * MB);
  float* Qf = (float*)(W + 32 * MB);
  float* Kf = (float*)(W + 48 * MB);
  float* Vf = (float*)(W + 64 * MB);
  short* Xnb = (short*)(W + 80 * MB);
  short* Qb2 = (short*)(W + 88 * MB);  // later reused as Gb
  short* Kb2 = (short*)(W + 96 * MB);
  short* Vtb = (short*)(W + 104 * MB);
  short* Wts = (short*)(W + 112 * MB);  // 9M shorts = 18MB
  float* ct = (float*)(W + 131 * MB);
  float* st = ct + Ss * 64;
  short* Hb = (short*)Qf;  // FFN hidden (bf16, 8M shorts = 16MB) aliases dead Qf

  short* Wqt = Wts + 0 * 1048576;
  short* Wkt = Wts + 1 * 1048576;
  short* Wvt = Wts + 2 * 1048576;
  short* Wgt = Wts + 3 * 1048576;
  short* Wot = Wts + 4 * 1048576;
  short* W1t = Wts + 5 * 1048576;  // [2048][1024]
  short* W2t = Wts + 7 * 1048576;  // [1024][2048]

  hipMemcpyAsync(Abuf, X, (size_t)Mm * Dd * sizeof(float), hipMemcpyDeviceToDevice, stream);
  rope_table_kernel<<<(Ss * 64) / 256, 256, 0, stream>>>(ct, st);

  const dim3 gD(Dd / 128, Mm / 64);   // N=1024
  const dim3 gF(Ff / 128, Mm / 64);   // N=2048
  const dim3 gW(32, 32), gW1(64, 32), gW2(32, 64);

  for (int l = 0; l < LAYERS; ++l) {
    const size_t DD = (size_t)Dd * Dd;
    // weight transpose-convert for this layer
    wtrans_kernel<<<gW, 256, 0, stream>>>(Wq + l * DD, Wqt, Dd, Dd);
    wtrans_kernel<<<gW, 256, 0, stream>>>(Wk + l * DD, Wkt, Dd, Dd);
    wtrans_kernel<<<gW, 256, 0, stream>>>(Wv + l * DD, Wvt, Dd, Dd);
    wtrans_kernel<<<gW, 256, 0, stream>>>(Wg + l * DD, Wgt, Dd, Dd);
    wtrans_kernel<<<gW, 256, 0, stream>>>(Wo + l * DD, Wot, Dd, Dd);
    wtrans_kernel<<<gW1, 256, 0, stream>>>(W1 + (size_t)l * Dd * Ff, W1t, Dd, Ff);
    wtrans_kernel<<<gW2, 256, 0, stream>>>(W2 + (size_t)l * Ff * Dd, W2t, Ff, Dd);

    // Xn = LN(A) -> bf16
    ln_bf16_kernel<<<Mm, 256, 0, stream>>>(Abuf, Xnb, lns, lnb);
    // Q,K,V projections (fp32 out)
    gemm_bf16<0, false><<<gD, 256, 0, stream>>>(Xnb, Wqt, Qf, nullptr, nullptr, nullptr, Dd, Dd);
    gemm_bf16<0, false><<<gD, 256, 0, stream>>>(Xnb, Wkt, Kf, nullptr, nullptr, nullptr, Dd, Dd);
    gemm_bf16<0, false><<<gD, 256, 0, stream>>>(Xnb, Wvt, Vf, nullptr, nullptr, nullptr, Dd, Dd);
    // RoPE -> bf16 Q,K ; V -> transposed bf16
    rope_bf16_kernel<<<(Bb * Ss * Hh * 64) / 256, 256, 0, stream>>>(Qf, Kf, Qb2, Kb2, ct, st);
    vtrans_kernel<<<dim3(Ss / 32, DHd / 32, Bb * Hh), 256, 0, stream>>>(Vf, Vtb);
    // retention + fused groupnorm -> Yf (fp32)
    ret_kernel<<<dim3(Bb * Hh, Ss / 64), 256, 0, stream>>>(Qb2, Kb2, Vtb, Yf,
                                                           gns + (size_t)l * Dd,
                                                           gnb + (size_t)l * Dd);
    // G = swish(Xn@Wg) * Yn -> bf16 (into Qb2)
    gemm_bf16<3, true><<<gD, 256, 0, stream>>>(Xnb, Wgt, nullptr, Qb2, nullptr, Yf, Dd, Dd);
    // A = G@Wo + A
    gemm_bf16<1, false><<<gD, 256, 0, stream>>>(Qb2, Wot, Abuf, nullptr, Abuf, nullptr, Dd, Dd);
    // FFN
    ln_bf16_kernel<<<Mm, 256, 0, stream>>>(Abuf, Xnb, lns, lnb);
    gemm_bf16<2, true><<<gF, 256, 0, stream>>>(Xnb, W1t, nullptr, Hb, nullptr, nullptr, Ff, Dd);
    float* dst = (l == LAYERS - 1) ? out : Abuf;
    gemm_bf16<1, false><<<gD, 256, 0, stream>>>(Hb, W2t, dst, nullptr, Abuf, nullptr, Dd, Ff);
  }
}

// Round 3
// 1014.388 us; speedup vs baseline: 7.0265x; 1.1406x over previous
//
#include <hip/hip_runtime.h>
#include <hip/hip_bf16.h>
#include <cmath>

#define LAYERS 4
#define Bb 4
#define Ss 1024
#define Dd 1024
#define Ff 2048
#define Hh 8
#define DHd 128
#define Mm (Bb * Ss)   // 4096 rows
#define EPSf 1e-5f

typedef __attribute__((ext_vector_type(8))) short short8v;
typedef __attribute__((ext_vector_type(4))) float f32x4;
typedef __attribute__((ext_vector_type(4))) unsigned int u32x4;

__device__ __forceinline__ float swish_f(float x) { return x / (1.f + expf(-x)); }
__device__ __forceinline__ float gelu_f(float x) {
  return 0.5f * x * (1.f + tanhf(0.7978845608028654f * (x + 0.044715f * x * x * x)));
}
__device__ __forceinline__ unsigned short f2bfu(float f) {
  __hip_bfloat16 h = __float2bfloat16(f);
  return __builtin_bit_cast(unsigned short, h);
}
__device__ __forceinline__ float bfu2f(unsigned short u) {
  unsigned v = ((unsigned)u) << 16;
  return __builtin_bit_cast(float, v);
}
__device__ __forceinline__ void gl_lds16(const void* g, void* l) {
  __builtin_amdgcn_global_load_lds((__attribute__((address_space(1))) void*)g,
                                   (__attribute__((address_space(3))) void*)l, 16, 0, 0);
}
__device__ __forceinline__ f32x4 mfma16(short8v a, short8v b, f32x4 c) {
  return __builtin_amdgcn_mfma_f32_16x16x32_bf16(a, b, c, 0, 0, 0);
}

// ---------------- LayerNorm fp32 -> bf16 ----------------
__global__ __launch_bounds__(256) void ln_bf16_kernel(const float* __restrict__ x,
                                                      short* __restrict__ outb,
                                                      const float* __restrict__ sc,
                                                      const float* __restrict__ bi) {
  const int row = blockIdx.x;
  const int t = threadIdx.x;
  const float4 v = *(const float4*)(x + (size_t)row * Dd + t * 4);
  float s = v.x + v.y + v.z + v.w;
  float s2 = v.x * v.x + v.y * v.y + v.z * v.z + v.w * v.w;
#pragma unroll
  for (int o = 32; o > 0; o >>= 1) { s += __shfl_down(s, o); s2 += __shfl_down(s2, o); }
  __shared__ float ps[4], ps2[4];
  if ((t & 63) == 0) { ps[t >> 6] = s; ps2[t >> 6] = s2; }
  __syncthreads();
  s = ps[0] + ps[1] + ps[2] + ps[3];
  s2 = ps2[0] + ps2[1] + ps2[2] + ps2[3];
  const float mu = s * (1.f / Dd);
  const float var = s2 * (1.f / Dd) - mu * mu;
  const float rstd = rsqrtf(var + EPSf);
  const float4 g = *(const float4*)(sc + t * 4);
  const float4 b = *(const float4*)(bi + t * 4);
  const float o0 = (v.x - mu) * rstd * g.x + b.x;
  const float o1 = (v.y - mu) * rstd * g.y + b.y;
  const float o2 = (v.z - mu) * rstd * g.z + b.z;
  const float o3 = (v.w - mu) * rstd * g.w + b.w;
  unsigned p0 = (unsigned)f2bfu(o0) | ((unsigned)f2bfu(o1) << 16);
  unsigned p1 = (unsigned)f2bfu(o2) | ((unsigned)f2bfu(o3) << 16);
  uint2 pk; pk.x = p0; pk.y = p1;
  *(uint2*)(outb + (size_t)row * Dd + t * 4) = pk;
}

// ---------------- RoPE tables ----------------
__global__ void rope_table_kernel(float* __restrict__ ct, float* __restrict__ st) {
  const int i = blockIdx.x * 256 + threadIdx.x;  // < Ss*64
  const int s = i >> 6, f = i & 63;
  const float inv = powf(10000.f, -(float)f / 64.f);
  const float a = (float)s * inv;
  ct[i] = cosf(a);
  st[i] = sinf(a);
}

// ---------------- RoPE apply fp32 -> bf16 (Q:+sin, K:-sin) ----------------
__global__ void rope_bf16_kernel(const float* __restrict__ Qf, const float* __restrict__ Kf,
                                 short* __restrict__ Qo, short* __restrict__ Ko,
                                 const float* __restrict__ ct, const float* __restrict__ st) {
  const int idx = blockIdx.x * 256 + threadIdx.x;  // < B*S*H*64 pairs
  const int f = idx & 63;
  const int s = (idx >> 9) & (Ss - 1);
  const size_t base = (size_t)(idx >> 6) * DHd + 2 * f;
  const float c = ct[(s << 6) + f], sn = st[(s << 6) + f];
  const float2 q = *(const float2*)(Qf + base);
  const float2 k = *(const float2*)(Kf + base);
  unsigned qp = (unsigned)f2bfu(q.x * c - q.y * sn) | ((unsigned)f2bfu(q.x * sn + q.y * c) << 16);
  unsigned kp = (unsigned)f2bfu(k.x * c + k.y * sn) | ((unsigned)f2bfu(-k.x * sn + k.y * c) << 16);
  *(unsigned*)(Qo + base) = qp;
  *(unsigned*)(Ko + base) = kp;
}

// ---------------- transpose-convert QKVG concat: 4x W[K][1024] fp32 -> Wt[4096][K] bf16 ----
__global__ __launch_bounds__(256) void wtrans4_kernel(const float* __restrict__ W0,
                                                      const float* __restrict__ W1,
                                                      const float* __restrict__ W2,
                                                      const float* __restrict__ W3,
                                                      short* __restrict__ Wt) {
  __shared__ float tile[32][33];
  const int t = threadIdx.x;
  const int n0 = blockIdx.x * 32, k0 = blockIdx.y * 32;
  const int which = n0 >> 10;
  const float* W = (which == 0) ? W0 : (which == 1) ? W1 : (which == 2) ? W2 : W3;
  const int nl = n0 & 1023;
  const int tc = t & 31, tr8 = t >> 5;
#pragma unroll
  for (int i = 0; i < 4; ++i) {
    const int r = tr8 + i * 8;
    tile[r][tc] = W[(size_t)(k0 + r) * 1024 + nl + tc];
  }
  __syncthreads();
#pragma unroll
  for (int i = 0; i < 4; ++i) {
    const int r = tr8 + i * 8;
    Wt[(size_t)(n0 + r) * 1024 + k0 + tc] = (short)f2bfu(tile[tc][r]);
  }
}

// ---------------- transpose-convert single: W[K][N] fp32 -> Wt[N][K] bf16 ----------------
__global__ __launch_bounds__(256) void wtrans1_kernel(const float* __restrict__ W,
                                                      short* __restrict__ Wt, int K, int N) {
  __shared__ float tile[32][33];
  const int t = threadIdx.x;
  const int n0 = blockIdx.x * 32, k0 = blockIdx.y * 32;
  const int tc = t & 31, tr8 = t >> 5;
#pragma unroll
  for (int i = 0; i < 4; ++i) {
    const int r = tr8 + i * 8;
    tile[r][tc] = W[(size_t)(k0 + r) * N + n0 + tc];
  }
  __syncthreads();
#pragma unroll
  for (int i = 0; i < 4; ++i) {
    const int r = tr8 + i * 8;
    Wt[(size_t)(n0 + r) * K + k0 + tc] = (short)f2bfu(tile[tc][r]);
  }
}

// ---------------- V transpose bf16: Vb [B*S][D-slice h] -> Vt [(bh*128+d)][S] ----------------
__global__ __launch_bounds__(256) void vtrans16_kernel(const short* __restrict__ Vb,
                                                       short* __restrict__ Vt) {
  __shared__ short tile[32][33];
  const int t = threadIdx.x;
  const int s0 = blockIdx.x * 32, d0 = blockIdx.y * 32, bh = blockIdx.z;
  const int bb = bh >> 3, h = bh & 7;
  const int tc = t & 31, tr8 = t >> 5;
#pragma unroll
  for (int i = 0; i < 4; ++i) {
    const int r = tr8 + i * 8;
    tile[r][tc] = Vb[(size_t)(bb * Ss + s0 + r) * Dd + h * DHd + d0 + tc];
  }
  __syncthreads();
#pragma unroll
  for (int i = 0; i < 4; ++i) {
    const int r = tr8 + i * 8;
    Vt[(size_t)(bh * DHd + d0 + r) * Ss + s0 + tc] = tile[tc][r];
  }
}

// ---------------- bf16 MFMA GEMM, m97-style: BM=128, BN in {128,64}, BK=32 ----------------
// 256 threads = 4 waves. BN=128: wave grid 2x2, tile 64x64 (4x4 frags).
//                        BN=64 : waves stacked, tile 32x64 (2x4 frags).
// EPI: 0 = QKVG route (Q,K fp32; V,G bf16), 1 = +Res fp32, 2 = gelu bf16
template <int BN, int EPI>
__global__ __launch_bounds__(256) void gemm3(const short* __restrict__ A,
                                             const short* __restrict__ Bt,
                                             float* __restrict__ Cf,
                                             short* __restrict__ Cb,
                                             const float* __restrict__ Res,
                                             float* __restrict__ Qf, float* __restrict__ Kf,
                                             short* __restrict__ Vb, short* __restrict__ Gb,
                                             int N, int K) {
  constexpr int MF = (BN == 128) ? 4 : 2;
  __shared__ __align__(16) short As[128 * 32];
  __shared__ __align__(16) short Bs[BN * 32];
  const int t = threadIdx.x;
  const int w = t >> 6, l = t & 63;
  const int lq = l >> 4, lr = l & 15;
  const int wr = (BN == 128) ? (w >> 1) : w;
  const int wc = (BN == 128) ? (w & 1) : 0;
  constexpr int WTM = (BN == 128) ? 64 : 32;
  const int row0 = blockIdx.y * 128, col0 = blockIdx.x * BN;
  f32x4 acc[MF][4] = {};

  // staging source pointers (linear LDS, linear global chunks)
  // A: 1024 chunks of 16B -> 16 wave-instr total? no: 128*32*2B/16B = 512 chunks -> 2/wave
  const int cA0 = (w * 2 + 0) * 64 + l, cA1 = (w * 2 + 1) * 64 + l;
  const short* AgA = A + (size_t)(row0 + (cA0 >> 2)) * K + (cA0 & 3) * 8;
  const short* AgB = A + (size_t)(row0 + (cA1 >> 2)) * K + (cA1 & 3) * 8;
  const short* Bg0;
  const short* Bg1 = nullptr;
  if (BN == 128) {
    Bg0 = Bt + (size_t)(col0 + (cA0 >> 2)) * K + (cA0 & 3) * 8;
    Bg1 = Bt + (size_t)(col0 + (cA1 >> 2)) * K + (cA1 & 3) * 8;
  } else {
    const int cB = w * 64 + l;  // 256 chunks
    Bg0 = Bt + (size_t)(col0 + (cB >> 2)) * K + (cB & 3) * 8;
  }

  for (int k0 = 0; k0 < K; k0 += 32) {
    __syncthreads();
    gl_lds16(AgA + k0, &As[(w * 2 + 0) * 512]);
    gl_lds16(AgB + k0, &As[(w * 2 + 1) * 512]);
    if (BN == 128) {
      gl_lds16(Bg0 + k0, &Bs[(w * 2 + 0) * 512]);
      gl_lds16(Bg1 + k0, &Bs[(w * 2 + 1) * 512]);
    } else {
      gl_lds16(Bg0 + k0, &Bs[w * 512]);
    }
    __syncthreads();
    short8v a[MF], b[4];
#pragma unroll
    for (int m = 0; m < MF; ++m) {
      const int row = wr * WTM + m * 16 + lr;
      a[m] = *(const short8v*)&As[row * 32 + lq * 8];
    }
#pragma unroll
    for (int n = 0; n < 4; ++n) {
      const int col = wc * 64 + n * 16 + lr;
      b[n] = *(const short8v*)&Bs[col * 32 + lq * 8];
    }
#pragma unroll
    for (int m = 0; m < MF; ++m)
#pragma unroll
      for (int n = 0; n < 4; ++n) acc[m][n] = mfma16(a[m], b[n], acc[m][n]);
  }

  const int sel = col0 >> 10;  // for EPI 0
  const int clb = col0 - (sel << 10);
#pragma unroll
  for (int m = 0; m < MF; ++m) {
#pragma unroll
    for (int n = 0; n < 4; ++n) {
#pragma unroll
      for (int r = 0; r < 4; ++r) {
        const int row = row0 + wr * WTM + m * 16 + lq * 4 + r;
        const int col = col0 + wc * 64 + n * 16 + lr;
        float v = acc[m][n][r];
        if (EPI == 0) {
          const int cl = clb + wc * 64 + n * 16 + lr;
          const size_t o = (size_t)row * 1024 + cl;
          if (sel == 0) Qf[o] = v;
          else if (sel == 1) Kf[o] = v;
          else if (sel == 2) Vb[o] = (short)f2bfu(v);
          else Gb[o] = (short)f2bfu(v);
        } else {
          const size_t o = (size_t)row * N + col;
          if (EPI == 1) Cf[o] = v + Res[o];
          else Cb[o] = (short)f2bfu(gelu_f(v));
        }
      }
    }
  }
}

// ---------------- Retention v3: QBLK=128 (4 waves x 32q), KVBLK=64, kv-split halves -------
__global__ __launch_bounds__(256) void ret3_kernel(const short* __restrict__ Qb,
                                                   const short* __restrict__ Kb,
                                                   const short* __restrict__ Vt,
                                                   float* __restrict__ Y0,
                                                   float* __restrict__ Y1) {
  __shared__ __align__(16) short Ks[64 * 128];
  __shared__ __align__(16) short Vs[128 * 64];
  const int t = threadIdx.x, w = t >> 6, l = t & 63;
  const int lq = l >> 4, lr = l & 15;
  const int u = blockIdx.x;
  const int half = u >> 8;
  const int v = u & 255;
  const int bh = v & 31, j = v >> 5;
  const int qb = half ? j : 7 - j;          // balanced pairing across CUs
  const int b = bh >> 3, h = bh & 7;
  const int q0 = qb * 128;
  const float lstep = (logf(1.f / 512.f) - logf(1.f / 32.f)) * (1.f / 7.f);
  const float gamma = 1.f - expf(logf(1.f / 32.f) + (float)h * lstep);
  const float l2g = logf(gamma) * 1.44269504f;  // log2(gamma)

  // hoist Q fragments (B-operand layout): qf[qn][ks]
  short8v qf[2][4];
#pragma unroll
  for (int qn = 0; qn < 2; ++qn)
#pragma unroll
    for (int ks = 0; ks < 4; ++ks)
      qf[qn][ks] = *(const short8v*)(Qb + (size_t)(b * Ss + q0 + w * 32 + qn * 16 + lr) * Dd +
                                     h * DHd + ks * 32 + lq * 8);

  // decay factor tables: cmf[mf]=g^(-16mf), csr[r]=g^(63-4lq-r)
  float cmf[4], csr[4];
#pragma unroll
  for (int mf = 0; mf < 4; ++mf) cmf[mf] = exp2f(l2g * (float)(-16 * mf));
#pragma unroll
  for (int r = 0; r < 4; ++r) csr[r] = exp2f(l2g * (float)(63 - 4 * lq - r));

  f32x4 yacc[2][8] = {};
  const int nt = 2 * qb + 2;
  const int sb = ((lq & 1) * 2) * 16 + lr;  // shuffle base lane

  for (int tt = half; tt < nt; tt += 2) {
    const int m0 = tt * 64;
    __syncthreads();
    // stage K tile 64x128 (1024 chunks, 16/row, xor(row&7) on chunk slot)
#pragma unroll
    for (int i = 0; i < 4; ++i) {
      const int c = (w * 4 + i) * 64 + l;
      const int row = c >> 4, slot = c & 15;
      gl_lds16(Kb + (size_t)(b * Ss + m0 + row) * Dd + h * DHd + ((slot ^ (row & 7)) * 8),
               &Ks[(w * 4 + i) * 512]);
    }
    // stage V^T tile 128x64 (1024 chunks, 8/row, xor(row&7))
#pragma unroll
    for (int i = 0; i < 4; ++i) {
      const int c = (w * 4 + i) * 64 + l;
      const int row = c >> 3, slot = c & 7;
      gl_lds16(Vt + (size_t)(bh * DHd + row) * Ss + m0 + ((slot ^ (row & 7)) * 8),
               &Vs[(w * 4 + i) * 512]);
    }
    __syncthreads();

    // St[kv][q] = K x Q^T  (swapped operands)
    f32x4 st[4][2] = {};
#pragma unroll
    for (int mf = 0; mf < 4; ++mf) {
      const int row = mf * 16 + lr;
#pragma unroll
      for (int ks = 0; ks < 4; ++ks) {
        short8v kf = *(const short8v*)&Ks[row * 128 + (((4 * ks + lq) ^ (row & 7)) * 8)];
        st[mf][0] = mfma16(kf, qf[0][ks], st[mf][0]);
        st[mf][1] = mfma16(kf, qf[1][ks], st[mf][1]);
      }
    }
    // decay: weight = g^(qg-kv) = rs(qn) * cmf[mf] * csr[r], masked qg>=kv
    float rs[2];
#pragma unroll
    for (int qn = 0; qn < 2; ++qn)
      rs[qn] = exp2f(l2g * (float)(q0 + w * 32 + qn * 16 + lr - m0 - 63));
#pragma unroll
    for (int mf = 0; mf < 4; ++mf)
#pragma unroll
      for (int qn = 0; qn < 2; ++qn)
#pragma unroll
        for (int r = 0; r < 4; ++r) {
          const int qg = q0 + w * 32 + qn * 16 + lr;
          const int kvg = m0 + mf * 16 + lq * 4 + r;
          const float wgt = (qg >= kvg) ? rs[qn] * cmf[mf] * csr[r] : 0.f;
          st[mf][qn][r] *= wgt;
        }
    // pack to bf16 pairs: pk[mf][qn][p] = (st[2p], st[2p+1])
    unsigned pk[4][2][2];
#pragma unroll
    for (int mf = 0; mf < 4; ++mf)
#pragma unroll
      for (int qn = 0; qn < 2; ++qn)
#pragma unroll
        for (int p = 0; p < 2; ++p)
          pk[mf][qn][p] = (unsigned)f2bfu(st[mf][qn][2 * p]) |
                          ((unsigned)f2bfu(st[mf][qn][2 * p + 1]) << 16);
    // gather PV A-fragments via shuffles: afr[qn][ks2]
    short8v afr[2][2];
#pragma unroll
    for (int qn = 0; qn < 2; ++qn)
#pragma unroll
      for (int ks2 = 0; ks2 < 2; ++ks2) {
        u32x4 wd;
#pragma unroll
        for (int wj = 0; wj < 4; ++wj) {
          const int src = sb + (wj >> 1) * 16;
          const unsigned v0 = __shfl(pk[2 * ks2 + 0][qn][wj & 1], src);
          const unsigned v1 = __shfl(pk[2 * ks2 + 1][qn][wj & 1], src);
          wd[wj] = (lq >= 2) ? v1 : v0;
        }
        afr[qn][ks2] = __builtin_bit_cast(short8v, wd);
      }
    // Y += S x V
#pragma unroll
    for (int nd = 0; nd < 8; ++nd) {
      const int row = nd * 16 + lr;
#pragma unroll
      for (int ks2 = 0; ks2 < 2; ++ks2) {
        short8v vf = *(const short8v*)&Vs[row * 64 + (((4 * ks2 + lq) ^ (row & 7)) * 8)];
        yacc[0][nd] = mfma16(afr[0][ks2], vf, yacc[0][nd]);
        yacc[1][nd] = mfma16(afr[1][ks2], vf, yacc[1][nd]);
      }
    }
  }
  float* Y = half ? Y1 : Y0;
#pragma unroll
  for (int qn = 0; qn < 2; ++qn)
#pragma unroll
    for (int r = 0; r < 4; ++r) {
      const int q = q0 + w * 32 + qn * 16 + lq * 4 + r;
#pragma unroll
      for (int nd = 0; nd < 8; ++nd)
        Y[(size_t)(b * Ss + q) * Dd + h * DHd + nd * 16 + lr] = yacc[qn][nd][r];
    }
}

// ---------------- gate: Gb = bf16( swish(Graw) * GN(Y0+Y1) ) ----------------
__global__ __launch_bounds__(256) void gate_kernel(const float* __restrict__ Y0,
                                                   const float* __restrict__ Y1,
                                                   const short* __restrict__ Graw,
                                                   short* __restrict__ Gb,
                                                   const float* __restrict__ gs,
                                                   const float* __restrict__ gb) {
  const int lane = threadIdx.x & 63;
  const int rowh = blockIdx.x * 4 + (threadIdx.x >> 6);  // (b*S+s)*H + h
  const int h = rowh & 7;
  const size_t base = (size_t)(rowh >> 3) * Dd + (size_t)h * DHd + lane * 2;
  float2 a = *(const float2*)(Y0 + base);
  const float2 c = *(const float2*)(Y1 + base);
  a.x += c.x; a.y += c.y;
  float s = a.x + a.y, s2 = a.x * a.x + a.y * a.y;
#pragma unroll
  for (int o = 32; o > 0; o >>= 1) { s += __shfl_down(s, o); s2 += __shfl_down(s2, o); }
  s = __shfl(s, 0);
  s2 = __shfl(s2, 0);
  const float mu = s * (1.f / DHd);
  const float rstd = rsqrtf(s2 * (1.f / DHd) - mu * mu + EPSf);
  const int d = h * DHd + lane * 2;
  const float2 g = *(const float2*)(gs + d);
  const float2 bbv = *(const float2*)(gb + d);
  const float y0 = (a.x - mu) * rstd * g.x + bbv.x;
  const float y1 = (a.y - mu) * rstd * g.y + bbv.y;
  const unsigned gr = *(const unsigned*)(Graw + base);
  const float gx = bfu2f((unsigned short)(gr & 0xffff));
  const float gy = bfu2f((unsigned short)(gr >> 16));
  const unsigned o01 = (unsigned)f2bfu(swish_f(gx) * y0) |
                       ((unsigned)f2bfu(swish_f(gy) * y1) << 16);
  *(unsigned*)(Gb + base) = o01;
}

extern "C" void kernel_launch(void* const* d_in, const int* in_sizes, int n_in,
                              void* d_out, int out_size, void* d_ws, size_t ws_size,
                              hipStream_t stream) {
  const float* X = (const float*)d_in[0];
  const float* Wq = (const float*)d_in[1];
  const float* Wk = (const float*)d_in[2];
  const float* Wv = (const float*)d_in[3];
  const float* Wg = (const float*)d_in[4];
  const float* Wo = (const float*)d_in[5];
  const float* W1 = (const float*)d_in[6];
  const float* W2 = (const float*)d_in[7];
  const float* lns = (const float*)d_in[8];
  const float* lnb = (const float*)d_in[9];
  const float* gns = (const float*)d_in[10];
  const float* gnb = (const float*)d_in[11];
  float* out = (float*)d_out;

  char* W = (char*)d_ws;
  const size_t MB = 1u << 20;
  float* Abuf = (float*)(W);            // 16 MB fp32
  short* Xnb  = (short*)(W + 16 * MB);  // 8 MB bf16
  float* Qf   = (float*)(W + 24 * MB);  // 16 MB fp32 (later Y0)
  float* Kf   = (float*)(W + 40 * MB);  // 16 MB fp32 (later Y1)
  short* Vb   = (short*)(W + 56 * MB);  // 8 MB bf16 (later gate out Gb)
  short* Graw = (short*)(W + 64 * MB);  // 8 MB bf16
  short* Qb2  = (short*)(W + 72 * MB);  // 8 MB bf16 (Hb aliases 72..88)
  short* Kb2  = (short*)(W + 80 * MB);  // 8 MB bf16
  short* Vtb  = (short*)(W + 88 * MB);  // 8 MB bf16
  short* Wqkvgt = (short*)(W + 96 * MB);   // 8 MB
  short* Wot  = (short*)(W + 104 * MB);    // 2 MB
  short* W1t  = (short*)(W + 106 * MB);    // 4 MB
  short* W2t  = (short*)(W + 110 * MB);    // 4 MB
  float* ct   = (float*)(W + 114 * MB);    // 256 KB
  float* st   = ct + Ss * 64;              // 256 KB
  float* Y0 = Qf;
  float* Y1 = Kf;
  short* Gb = Vb;
  short* Hb = Qb2;  // 16 MB (Qb2+Kb2 region)

  hipMemcpyAsync(Abuf, X, (size_t)Mm * Dd * sizeof(float), hipMemcpyDeviceToDevice, stream);
  rope_table_kernel<<<(Ss * 64) / 256, 256, 0, stream>>>(ct, st);

  for (int l = 0; l < LAYERS; ++l) {
    const size_t DD = (size_t)Dd * Dd;
    wtrans4_kernel<<<dim3(128, 32), 256, 0, stream>>>(Wq + l * DD, Wk + l * DD, Wv + l * DD,
                                                      Wg + l * DD, Wqkvgt);
    wtrans1_kernel<<<dim3(32, 32), 256, 0, stream>>>(Wo + l * DD, Wot, Dd, Dd);
    wtrans1_kernel<<<dim3(64, 32), 256, 0, stream>>>(W1 + (size_t)l * Dd * Ff, W1t, Dd, Ff);
    wtrans1_kernel<<<dim3(32, 64), 256, 0, stream>>>(W2 + (size_t)l * Ff * Dd, W2t, Ff, Dd);

    // Xn = LN(A) -> bf16
    ln_bf16_kernel<<<Mm, 256, 0, stream>>>(Abuf, Xnb, lns, lnb);
    // fused QKVG projection (N=4096)
    gemm3<128, 0><<<dim3(32, 32), 256, 0, stream>>>(Xnb, Wqkvgt, nullptr, nullptr, nullptr,
                                                    Qf, Kf, Vb, Graw, 4096, Dd);
    // RoPE Q,K -> bf16
    rope_bf16_kernel<<<(Bb * Ss * Hh * 64) / 256, 256, 0, stream>>>(Qf, Kf, Qb2, Kb2, ct, st);
    // V transpose
    vtrans16_kernel<<<dim3(Ss / 32, DHd / 32, Bb * Hh), 256, 0, stream>>>(Vb, Vtb);
    // retention -> partial Y0,Y1 (fp32)
    ret3_kernel<<<512, 256, 0, stream>>>(Qb2, Kb2, Vtb, Y0, Y1);
    // gate: Gb = swish(Graw) * GN(Y0+Y1)
    gate_kernel<<<(Mm * Hh) / 4, 256, 0, stream>>>(Y0, Y1, Graw, Gb,
                                                   gns + (size_t)l * Dd, gnb + (size_t)l * Dd);
    // A = (Gb @ Wo) + A
    gemm3<64, 1><<<dim3(16, 32), 256, 0, stream>>>(Gb, Wot, Abuf, nullptr, Abuf,
                                                   nullptr, nullptr, nullptr, nullptr, Dd, Dd);
    // FFN
    ln_bf16_kernel<<<Mm, 256, 0, stream>>>(Abuf, Xnb, lns, lnb);
    gemm3<128, 2><<<dim3(16, 32), 256, 0, stream>>>(Xnb, W1t, nullptr, Hb, nullptr,
                                                    nullptr, nullptr, nullptr, nullptr, Ff, Dd);
    float* dst = (l == LAYERS - 1) ? out : Abuf;
    gemm3<64, 1><<<dim3(16, 32), 256, 0, stream>>>(Hb, W2t, dst, nullptr, Abuf,
                                                   nullptr, nullptr, nullptr, nullptr, Dd, Ff);
  }
}

// Round 4
// 977.074 us; speedup vs baseline: 7.2949x; 1.0382x over previous
//
#include <hip/hip_runtime.h>
#include <hip/hip_bf16.h>
#include <cmath>

#define LAYERS 4
#define Bb 4
#define Ss 1024
#define Dd 1024
#define Ff 2048
#define Hh 8
#define DHd 128
#define Mm (Bb * Ss)   // 4096 rows
#define EPSf 1e-5f

typedef __attribute__((ext_vector_type(8))) short short8v;
typedef __attribute__((ext_vector_type(4))) float f32x4;
typedef __attribute__((ext_vector_type(4))) unsigned int u32x4;

__device__ __forceinline__ float swish_f(float x) { return x / (1.f + expf(-x)); }
__device__ __forceinline__ float gelu_f(float x) {
  return 0.5f * x * (1.f + tanhf(0.7978845608028654f * (x + 0.044715f * x * x * x)));
}
__device__ __forceinline__ unsigned short f2bfu(float f) {
  __hip_bfloat16 h = __float2bfloat16(f);
  return __builtin_bit_cast(unsigned short, h);
}
__device__ __forceinline__ float bfu2f(unsigned short u) {
  unsigned v = ((unsigned)u) << 16;
  return __builtin_bit_cast(float, v);
}
__device__ __forceinline__ void gl_lds16(const void* g, void* l) {
  __builtin_amdgcn_global_load_lds((__attribute__((address_space(1))) void*)g,
                                   (__attribute__((address_space(3))) void*)l, 16, 0, 0);
}
__device__ __forceinline__ f32x4 mfma16(short8v a, short8v b, f32x4 c) {
  return __builtin_amdgcn_mfma_f32_16x16x32_bf16(a, b, c, 0, 0, 0);
}

// ---------------- LayerNorm fp32 -> bf16 ----------------
__global__ __launch_bounds__(256) void ln_bf16_kernel(const float* __restrict__ x,
                                                      short* __restrict__ outb,
                                                      const float* __restrict__ sc,
                                                      const float* __restrict__ bi) {
  const int row = blockIdx.x;
  const int t = threadIdx.x;
  const float4 v = *(const float4*)(x + (size_t)row * Dd + t * 4);
  float s = v.x + v.y + v.z + v.w;
  float s2 = v.x * v.x + v.y * v.y + v.z * v.z + v.w * v.w;
#pragma unroll
  for (int o = 32; o > 0; o >>= 1) { s += __shfl_down(s, o); s2 += __shfl_down(s2, o); }
  __shared__ float ps[4], ps2[4];
  if ((t & 63) == 0) { ps[t >> 6] = s; ps2[t >> 6] = s2; }
  __syncthreads();
  s = ps[0] + ps[1] + ps[2] + ps[3];
  s2 = ps2[0] + ps2[1] + ps2[2] + ps2[3];
  const float mu = s * (1.f / Dd);
  const float var = s2 * (1.f / Dd) - mu * mu;
  const float rstd = rsqrtf(var + EPSf);
  const float4 g = *(const float4*)(sc + t * 4);
  const float4 b = *(const float4*)(bi + t * 4);
  const float o0 = (v.x - mu) * rstd * g.x + b.x;
  const float o1 = (v.y - mu) * rstd * g.y + b.y;
  const float o2 = (v.z - mu) * rstd * g.z + b.z;
  const float o3 = (v.w - mu) * rstd * g.w + b.w;
  unsigned p0 = (unsigned)f2bfu(o0) | ((unsigned)f2bfu(o1) << 16);
  unsigned p1 = (unsigned)f2bfu(o2) | ((unsigned)f2bfu(o3) << 16);
  uint2 pk; pk.x = p0; pk.y = p1;
  *(uint2*)(outb + (size_t)row * Dd + t * 4) = pk;
}

// ---------------- RoPE tables ----------------
__global__ void rope_table_kernel(float* __restrict__ ct, float* __restrict__ st) {
  const int i = blockIdx.x * 256 + threadIdx.x;  // < Ss*64
  const int s = i >> 6, f = i & 63;
  const float inv = powf(10000.f, -(float)f / 64.f);
  const float a = (float)s * inv;
  ct[i] = cosf(a);
  st[i] = sinf(a);
}

// ---------------- RoPE apply fp32 -> bf16 (Q:+sin, K:-sin) ----------------
__global__ void rope_bf16_kernel(const float* __restrict__ Qf, const float* __restrict__ Kf,
                                 short* __restrict__ Qo, short* __restrict__ Ko,
                                 const float* __restrict__ ct, const float* __restrict__ st) {
  const int idx = blockIdx.x * 256 + threadIdx.x;  // < B*S*H*64 pairs
  const int f = idx & 63;
  const int s = (idx >> 9) & (Ss - 1);
  const size_t base = (size_t)(idx >> 6) * DHd + 2 * f;
  const float c = ct[(s << 6) + f], sn = st[(s << 6) + f];
  const float2 q = *(const float2*)(Qf + base);
  const float2 k = *(const float2*)(Kf + base);
  unsigned qp = (unsigned)f2bfu(q.x * c - q.y * sn) | ((unsigned)f2bfu(q.x * sn + q.y * c) << 16);
  unsigned kp = (unsigned)f2bfu(k.x * c + k.y * sn) | ((unsigned)f2bfu(-k.x * sn + k.y * c) << 16);
  *(unsigned*)(Qo + base) = qp;
  *(unsigned*)(Ko + base) = kp;
}

// ---------------- transpose-convert QKVG concat: 4x W[K][1024] fp32 -> Wt[4096][K] bf16 ----
__global__ __launch_bounds__(256) void wtrans4_kernel(const float* __restrict__ W0,
                                                      const float* __restrict__ W1,
                                                      const float* __restrict__ W2,
                                                      const float* __restrict__ W3,
                                                      short* __restrict__ Wt) {
  __shared__ float tile[32][33];
  const int t = threadIdx.x;
  const int n0 = blockIdx.x * 32, k0 = blockIdx.y * 32;
  const int which = n0 >> 10;
  const float* W = (which == 0) ? W0 : (which == 1) ? W1 : (which == 2) ? W2 : W3;
  const int nl = n0 & 1023;
  const int tc = t & 31, tr8 = t >> 5;
#pragma unroll
  for (int i = 0; i < 4; ++i) {
    const int r = tr8 + i * 8;
    tile[r][tc] = W[(size_t)(k0 + r) * 1024 + nl + tc];
  }
  __syncthreads();
#pragma unroll
  for (int i = 0; i < 4; ++i) {
    const int r = tr8 + i * 8;
    Wt[(size_t)(n0 + r) * 1024 + k0 + tc] = (short)f2bfu(tile[tc][r]);
  }
}

// ---------------- transpose-convert single: W[K][N] fp32 -> Wt[N][K] bf16 ----------------
__global__ __launch_bounds__(256) void wtrans1_kernel(const float* __restrict__ W,
                                                      short* __restrict__ Wt, int K, int N) {
  __shared__ float tile[32][33];
  const int t = threadIdx.x;
  const int n0 = blockIdx.x * 32, k0 = blockIdx.y * 32;
  const int tc = t & 31, tr8 = t >> 5;
#pragma unroll
  for (int i = 0; i < 4; ++i) {
    const int r = tr8 + i * 8;
    tile[r][tc] = W[(size_t)(k0 + r) * N + n0 + tc];
  }
  __syncthreads();
#pragma unroll
  for (int i = 0; i < 4; ++i) {
    const int r = tr8 + i * 8;
    Wt[(size_t)(n0 + r) * K + k0 + tc] = (short)f2bfu(tile[tc][r]);
  }
}

// ---------------- V transpose bf16: Vb [B*S][D-slice h] -> Vt [(bh*128+d)][S] ----------------
__global__ __launch_bounds__(256) void vtrans16_kernel(const short* __restrict__ Vb,
                                                       short* __restrict__ Vt) {
  __shared__ short tile[32][33];
  const int t = threadIdx.x;
  const int s0 = blockIdx.x * 32, d0 = blockIdx.y * 32, bh = blockIdx.z;
  const int bb = bh >> 3, h = bh & 7;
  const int tc = t & 31, tr8 = t >> 5;
#pragma unroll
  for (int i = 0; i < 4; ++i) {
    const int r = tr8 + i * 8;
    tile[r][tc] = Vb[(size_t)(bb * Ss + s0 + r) * Dd + h * DHd + d0 + tc];
  }
  __syncthreads();
#pragma unroll
  for (int i = 0; i < 4; ++i) {
    const int r = tr8 + i * 8;
    Vt[(size_t)(bh * DHd + d0 + r) * Ss + s0 + tc] = tile[tc][r];
  }
}

// ---------------- bf16 MFMA GEMM v4: dbuf LDS, 1 barrier/K-step, XCD swizzle ----------------
// BM=128, BN in {128,64}, BK=32; 256 threads = 4 waves.
// EPI: 0 = QKVG route (Q,K fp32; V,G bf16), 1 = +Res fp32, 2 = gelu bf16
template <int BN, int EPI>
__global__ __launch_bounds__(256) void gemm4(const short* __restrict__ A,
                                             const short* __restrict__ Bt,
                                             float* __restrict__ Cf,
                                             short* __restrict__ Cb,
                                             const float* __restrict__ Res,
                                             float* __restrict__ Qf, float* __restrict__ Kf,
                                             short* __restrict__ Vb, short* __restrict__ Gb,
                                             int N, int K) {
  constexpr int MF = (BN == 128) ? 4 : 2;
  __shared__ __align__(16) short As[2][128 * 32];
  __shared__ __align__(16) short Bs[2][BN * 32];
  const int t = threadIdx.x;
  const int w = t >> 6, l = t & 63;
  const int lq = l >> 4, lr = l & 15;
  const int wr = (BN == 128) ? (w >> 1) : w;
  const int wc = (BN == 128) ? (w & 1) : 0;
  constexpr int WTM = (BN == 128) ? 64 : 32;
  // T1: bijective XCD swizzle (nwg % 8 == 0 for all our grids)
  const int nwg = gridDim.x * gridDim.y;
  const int bid0 = blockIdx.x + blockIdx.y * gridDim.x;
  const int lgid = (bid0 & 7) * (nwg >> 3) + (bid0 >> 3);
  const int bx = lgid % gridDim.x, by = lgid / gridDim.x;
  const int row0 = by * 128, col0 = bx * BN;
  f32x4 acc[MF][4] = {};

  const int cA0 = (w * 2 + 0) * 64 + l, cA1 = (w * 2 + 1) * 64 + l;
  const short* AgA = A + (size_t)(row0 + (cA0 >> 2)) * K + (cA0 & 3) * 8;
  const short* AgB = A + (size_t)(row0 + (cA1 >> 2)) * K + (cA1 & 3) * 8;
  const short* Bg0;
  const short* Bg1 = nullptr;
  if (BN == 128) {
    Bg0 = Bt + (size_t)(col0 + (cA0 >> 2)) * K + (cA0 & 3) * 8;
    Bg1 = Bt + (size_t)(col0 + (cA1 >> 2)) * K + (cA1 & 3) * 8;
  } else {
    const int cB = w * 64 + l;
    Bg0 = Bt + (size_t)(col0 + (cB >> 2)) * K + (cB & 3) * 8;
  }

  auto stage = [&](int k0, int buf) {
    gl_lds16(AgA + k0, &As[buf][(w * 2 + 0) * 512]);
    gl_lds16(AgB + k0, &As[buf][(w * 2 + 1) * 512]);
    if (BN == 128) {
      gl_lds16(Bg0 + k0, &Bs[buf][(w * 2 + 0) * 512]);
      gl_lds16(Bg1 + k0, &Bs[buf][(w * 2 + 1) * 512]);
    } else {
      gl_lds16(Bg0 + k0, &Bs[buf][w * 512]);
    }
  };

  stage(0, 0);
  __syncthreads();
  int cur = 0;
  for (int k0 = 0; k0 < K; k0 += 32) {
    if (k0 + 32 < K) stage(k0 + 32, cur ^ 1);
    short8v a[MF], b[4];
#pragma unroll
    for (int m = 0; m < MF; ++m) {
      const int row = wr * WTM + m * 16 + lr;
      a[m] = *(const short8v*)&As[cur][row * 32 + lq * 8];
    }
#pragma unroll
    for (int n = 0; n < 4; ++n) {
      const int col = wc * 64 + n * 16 + lr;
      b[n] = *(const short8v*)&Bs[cur][col * 32 + lq * 8];
    }
#pragma unroll
    for (int m = 0; m < MF; ++m)
#pragma unroll
      for (int n = 0; n < 4; ++n) acc[m][n] = mfma16(a[m], b[n], acc[m][n]);
    __syncthreads();  // drains stage loads (vmcnt0) + frees As[cur] for overwrite
    cur ^= 1;
  }

  const int sel = col0 >> 10;  // for EPI 0
  const int clb = col0 - (sel << 10);
#pragma unroll
  for (int m = 0; m < MF; ++m) {
#pragma unroll
    for (int n = 0; n < 4; ++n) {
#pragma unroll
      for (int r = 0; r < 4; ++r) {
        const int row = row0 + wr * WTM + m * 16 + lq * 4 + r;
        const int col = col0 + wc * 64 + n * 16 + lr;
        float v = acc[m][n][r];
        if (EPI == 0) {
          const int cl = clb + wc * 64 + n * 16 + lr;
          const size_t o = (size_t)row * 1024 + cl;
          if (sel == 0) Qf[o] = v;
          else if (sel == 1) Kf[o] = v;
          else if (sel == 2) Vb[o] = (short)f2bfu(v);
          else Gb[o] = (short)f2bfu(v);
        } else {
          const size_t o = (size_t)row * N + col;
          if (EPI == 1) Cf[o] = v + Res[o];
          else Cb[o] = (short)f2bfu(gelu_f(v));
        }
      }
    }
  }
}

// ---------------- Retention v4: dbuf K/V, 1 barrier/tile, setprio, XCD-local bh ----------
__global__ __launch_bounds__(256) void ret4_kernel(const short* __restrict__ Qb,
                                                   const short* __restrict__ Kb,
                                                   const short* __restrict__ Vt,
                                                   float* __restrict__ Y0,
                                                   float* __restrict__ Y1) {
  __shared__ __align__(16) short Ks[2][64 * 128];
  __shared__ __align__(16) short Vs[2][128 * 64];
  const int t = threadIdx.x, w = t >> 6, l = t & 63;
  const int lq = l >> 4, lr = l & 15;
  // XCD-contiguous ordering: each XCD gets one kv-half of 8 bh panels (~4MB K+V, fits L2).
  const int u = blockIdx.x;                 // 0..511
  const int lgid = (u & 7) * 64 + (u >> 3);
  const int half = lgid >> 8;
  const int rest = lgid & 255;
  const int bh = rest >> 3, j = rest & 7;
  const int qb = half ? j : 7 - j;          // dispatch-order-balanced triangular pairing
  const int b = bh >> 3, h = bh & 7;
  const int q0 = qb * 128;
  const float lstep = (logf(1.f / 512.f) - logf(1.f / 32.f)) * (1.f / 7.f);
  const float gamma = 1.f - expf(logf(1.f / 32.f) + (float)h * lstep);
  const float l2g = logf(gamma) * 1.44269504f;  // log2(gamma)

  // hoist Q fragments (B-operand layout): qf[qn][ks]
  short8v qf[2][4];
#pragma unroll
  for (int qn = 0; qn < 2; ++qn)
#pragma unroll
    for (int ks = 0; ks < 4; ++ks)
      qf[qn][ks] = *(const short8v*)(Qb + (size_t)(b * Ss + q0 + w * 32 + qn * 16 + lr) * Dd +
                                     h * DHd + ks * 32 + lq * 8);

  // decay factor tables: cmf[mf]=g^(-16mf), csr[r]=g^(63-4lq-r)
  float cmf[4], csr[4];
#pragma unroll
  for (int mf = 0; mf < 4; ++mf) cmf[mf] = exp2f(l2g * (float)(-16 * mf));
#pragma unroll
  for (int r = 0; r < 4; ++r) csr[r] = exp2f(l2g * (float)(63 - 4 * lq - r));

  f32x4 yacc[2][8] = {};
  const int nt = 2 * qb + 2;
  const int sb = ((lq & 1) * 2) * 16 + lr;  // shuffle base lane

  auto stageKV = [&](int m0, int buf) {
#pragma unroll
    for (int i = 0; i < 4; ++i) {
      const int c = (w * 4 + i) * 64 + l;
      const int row = c >> 4, slot = c & 15;
      gl_lds16(Kb + (size_t)(b * Ss + m0 + row) * Dd + h * DHd + ((slot ^ (row & 7)) * 8),
               &Ks[buf][(w * 4 + i) * 512]);
    }
#pragma unroll
    for (int i = 0; i < 4; ++i) {
      const int c = (w * 4 + i) * 64 + l;
      const int row = c >> 3, slot = c & 7;
      gl_lds16(Vt + (size_t)(bh * DHd + row) * Ss + m0 + ((slot ^ (row & 7)) * 8),
               &Vs[buf][(w * 4 + i) * 512]);
    }
  };

  stageKV(half * 64, 0);
  __syncthreads();
  int cur = 0;
  for (int tt = half; tt < nt; tt += 2) {
    const int m0 = tt * 64;
    if (tt + 2 < nt) stageKV((tt + 2) * 64, cur ^ 1);

    // St[kv][q] = K x Q^T  (swapped operands)
    f32x4 st[4][2] = {};
    __builtin_amdgcn_s_setprio(1);
#pragma unroll
    for (int mf = 0; mf < 4; ++mf) {
      const int row = mf * 16 + lr;
#pragma unroll
      for (int ks = 0; ks < 4; ++ks) {
        short8v kf = *(const short8v*)&Ks[cur][row * 128 + (((4 * ks + lq) ^ (row & 7)) * 8)];
        st[mf][0] = mfma16(kf, qf[0][ks], st[mf][0]);
        st[mf][1] = mfma16(kf, qf[1][ks], st[mf][1]);
      }
    }
    __builtin_amdgcn_s_setprio(0);
    // decay: weight = g^(qg-kv) = rs(qn) * cmf[mf] * csr[r], masked qg>=kv
    float rs[2];
#pragma unroll
    for (int qn = 0; qn < 2; ++qn)
      rs[qn] = exp2f(l2g * (float)(q0 + w * 32 + qn * 16 + lr - m0 - 63));
#pragma unroll
    for (int mf = 0; mf < 4; ++mf)
#pragma unroll
      for (int qn = 0; qn < 2; ++qn)
#pragma unroll
        for (int r = 0; r < 4; ++r) {
          const int qg = q0 + w * 32 + qn * 16 + lr;
          const int kvg = m0 + mf * 16 + lq * 4 + r;
          const float wgt = (qg >= kvg) ? rs[qn] * cmf[mf] * csr[r] : 0.f;
          st[mf][qn][r] *= wgt;
        }
    // pack to bf16 pairs
    unsigned pk[4][2][2];
#pragma unroll
    for (int mf = 0; mf < 4; ++mf)
#pragma unroll
      for (int qn = 0; qn < 2; ++qn)
#pragma unroll
        for (int p = 0; p < 2; ++p)
          pk[mf][qn][p] = (unsigned)f2bfu(st[mf][qn][2 * p]) |
                          ((unsigned)f2bfu(st[mf][qn][2 * p + 1]) << 16);
    // gather PV A-fragments via shuffles
    short8v afr[2][2];
#pragma unroll
    for (int qn = 0; qn < 2; ++qn)
#pragma unroll
      for (int ks2 = 0; ks2 < 2; ++ks2) {
        u32x4 wd;
#pragma unroll
        for (int wj = 0; wj < 4; ++wj) {
          const int src = sb + (wj >> 1) * 16;
          const unsigned v0 = __shfl(pk[2 * ks2 + 0][qn][wj & 1], src);
          const unsigned v1 = __shfl(pk[2 * ks2 + 1][qn][wj & 1], src);
          wd[wj] = (lq >= 2) ? v1 : v0;
        }
        afr[qn][ks2] = __builtin_bit_cast(short8v, wd);
      }
    // Y += S x V
    __builtin_amdgcn_s_setprio(1);
#pragma unroll
    for (int nd = 0; nd < 8; ++nd) {
      const int row = nd * 16 + lr;
#pragma unroll
      for (int ks2 = 0; ks2 < 2; ++ks2) {
        short8v vf = *(const short8v*)&Vs[cur][row * 64 + (((4 * ks2 + lq) ^ (row & 7)) * 8)];
        yacc[0][nd] = mfma16(afr[0][ks2], vf, yacc[0][nd]);
        yacc[1][nd] = mfma16(afr[1][ks2], vf, yacc[1][nd]);
      }
    }
    __builtin_amdgcn_s_setprio(0);
    __syncthreads();  // drains stage (vmcnt0) + frees Ks/Vs[cur]
    cur ^= 1;
  }
  float* Y = half ? Y1 : Y0;
#pragma unroll
  for (int qn = 0; qn < 2; ++qn)
#pragma unroll
    for (int r = 0; r < 4; ++r) {
      const int q = q0 + w * 32 + qn * 16 + lq * 4 + r;
#pragma unroll
      for (int nd = 0; nd < 8; ++nd)
        Y[(size_t)(b * Ss + q) * Dd + h * DHd + nd * 16 + lr] = yacc[qn][nd][r];
    }
}

// ---------------- gate: Gb = bf16( swish(Graw) * GN(Y0+Y1) ) ----------------
__global__ __launch_bounds__(256) void gate_kernel(const float* __restrict__ Y0,
                                                   const float* __restrict__ Y1,
                                                   const short* __restrict__ Graw,
                                                   short* __restrict__ Gb,
                                                   const float* __restrict__ gs,
                                                   const float* __restrict__ gb) {
  const int lane = threadIdx.x & 63;
  const int rowh = blockIdx.x * 4 + (threadIdx.x >> 6);  // (b*S+s)*H + h
  const int h = rowh & 7;
  const size_t base = (size_t)(rowh >> 3) * Dd + (size_t)h * DHd + lane * 2;
  float2 a = *(const float2*)(Y0 + base);
  const float2 c = *(const float2*)(Y1 + base);
  a.x += c.x; a.y += c.y;
  float s = a.x + a.y, s2 = a.x * a.x + a.y * a.y;
#pragma unroll
  for (int o = 32; o > 0; o >>= 1) { s += __shfl_down(s, o); s2 += __shfl_down(s2, o); }
  s = __shfl(s, 0);
  s2 = __shfl(s2, 0);
  const float mu = s * (1.f / DHd);
  const float rstd = rsqrtf(s2 * (1.f / DHd) - mu * mu + EPSf);
  const int d = h * DHd + lane * 2;
  const float2 g = *(const float2*)(gs + d);
  const float2 bbv = *(const float2*)(gb + d);
  const float y0 = (a.x - mu) * rstd * g.x + bbv.x;
  const float y1 = (a.y - mu) * rstd * g.y + bbv.y;
  const unsigned gr = *(const unsigned*)(Graw + base);
  const float gx = bfu2f((unsigned short)(gr & 0xffff));
  const float gy = bfu2f((unsigned short)(gr >> 16));
  const unsigned o01 = (unsigned)f2bfu(swish_f(gx) * y0) |
                       ((unsigned)f2bfu(swish_f(gy) * y1) << 16);
  *(unsigned*)(Gb + base) = o01;
}

extern "C" void kernel_launch(void* const* d_in, const int* in_sizes, int n_in,
                              void* d_out, int out_size, void* d_ws, size_t ws_size,
                              hipStream_t stream) {
  const float* X = (const float*)d_in[0];
  const float* Wq = (const float*)d_in[1];
  const float* Wk = (const float*)d_in[2];
  const float* Wv = (const float*)d_in[3];
  const float* Wg = (const float*)d_in[4];
  const float* Wo = (const float*)d_in[5];
  const float* W1 = (const float*)d_in[6];
  const float* W2 = (const float*)d_in[7];
  const float* lns = (const float*)d_in[8];
  const float* lnb = (const float*)d_in[9];
  const float* gns = (const float*)d_in[10];
  const float* gnb = (const float*)d_in[11];
  float* out = (float*)d_out;

  char* W = (char*)d_ws;
  const size_t MB = 1u << 20;
  float* Abuf = (float*)(W);            // 16 MB fp32
  short* Xnb  = (short*)(W + 16 * MB);  // 8 MB bf16
  float* Qf   = (float*)(W + 24 * MB);  // 16 MB fp32 (later Y0)
  float* Kf   = (float*)(W + 40 * MB);  // 16 MB fp32 (later Y1)
  short* Vb   = (short*)(W + 56 * MB);  // 8 MB bf16 (later gate out Gb)
  short* Graw = (short*)(W + 64 * MB);  // 8 MB bf16
  short* Qb2  = (short*)(W + 72 * MB);  // 8 MB bf16 (Hb aliases 72..88)
  short* Kb2  = (short*)(W + 80 * MB);  // 8 MB bf16
  short* Vtb  = (short*)(W + 88 * MB);  // 8 MB bf16
  short* Wqkvgt = (short*)(W + 96 * MB);   // 8 MB
  short* Wot  = (short*)(W + 104 * MB);    // 2 MB
  short* W1t  = (short*)(W + 106 * MB);    // 4 MB
  short* W2t  = (short*)(W + 110 * MB);    // 4 MB
  float* ct   = (float*)(W + 114 * MB);    // 256 KB
  float* st   = ct + Ss * 64;              // 256 KB
  float* Y0 = Qf;
  float* Y1 = Kf;
  short* Gb = Vb;
  short* Hb = Qb2;  // 16 MB (Qb2+Kb2 region)

  hipMemcpyAsync(Abuf, X, (size_t)Mm * Dd * sizeof(float), hipMemcpyDeviceToDevice, stream);
  rope_table_kernel<<<(Ss * 64) / 256, 256, 0, stream>>>(ct, st);

  for (int l = 0; l < LAYERS; ++l) {
    const size_t DD = (size_t)Dd * Dd;
    wtrans4_kernel<<<dim3(128, 32), 256, 0, stream>>>(Wq + l * DD, Wk + l * DD, Wv + l * DD,
                                                      Wg + l * DD, Wqkvgt);
    wtrans1_kernel<<<dim3(32, 32), 256, 0, stream>>>(Wo + l * DD, Wot, Dd, Dd);
    wtrans1_kernel<<<dim3(64, 32), 256, 0, stream>>>(W1 + (size_t)l * Dd * Ff, W1t, Dd, Ff);
    wtrans1_kernel<<<dim3(32, 64), 256, 0, stream>>>(W2 + (size_t)l * Ff * Dd, W2t, Ff, Dd);

    // Xn = LN(A) -> bf16
    ln_bf16_kernel<<<Mm, 256, 0, stream>>>(Abuf, Xnb, lns, lnb);
    // fused QKVG projection (N=4096)
    gemm4<128, 0><<<dim3(32, 32), 256, 0, stream>>>(Xnb, Wqkvgt, nullptr, nullptr, nullptr,
                                                    Qf, Kf, Vb, Graw, 4096, Dd);
    // RoPE Q,K -> bf16
    rope_bf16_kernel<<<(Bb * Ss * Hh * 64) / 256, 256, 0, stream>>>(Qf, Kf, Qb2, Kb2, ct, st);
    // V transpose
    vtrans16_kernel<<<dim3(Ss / 32, DHd / 32, Bb * Hh), 256, 0, stream>>>(Vb, Vtb);
    // retention -> partial Y0,Y1 (fp32)
    ret4_kernel<<<512, 256, 0, stream>>>(Qb2, Kb2, Vtb, Y0, Y1);
    // gate: Gb = swish(Graw) * GN(Y0+Y1)
    gate_kernel<<<(Mm * Hh) / 4, 256, 0, stream>>>(Y0, Y1, Graw, Gb,
                                                   gns + (size_t)l * Dd, gnb + (size_t)l * Dd);
    // A = (Gb @ Wo) + A
    gemm4<64, 1><<<dim3(16, 32), 256, 0, stream>>>(Gb, Wot, Abuf, nullptr, Abuf,
                                                   nullptr, nullptr, nullptr, nullptr, Dd, Dd);
    // FFN
    ln_bf16_kernel<<<Mm, 256, 0, stream>>>(Abuf, Xnb, lns, lnb);
    gemm4<128, 2><<<dim3(16, 32), 256, 0, stream>>>(Xnb, W1t, nullptr, Hb, nullptr,
                                                    nullptr, nullptr, nullptr, nullptr, Ff, Dd);
    float* dst = (l == LAYERS - 1) ? out : Abuf;
    gemm4<64, 1><<<dim3(16, 32), 256, 0, stream>>>(Hb, W2t, dst, nullptr, Abuf,
                                                   nullptr, nullptr, nullptr, nullptr, Dd, Ff);
  }
}